// Round 8
// baseline (260.137 us; speedup 1.0000x reference)
//
#include <hip/hip_runtime.h>
#include <hip/hip_bf16.h>
#include <stdint.h>

#define B_ 8
#define K_ 2048
#define D_ 1024
#define NC 32
#define TC (K_ / NC)   // 64 timesteps per chunk

typedef float v4f __attribute__((ext_vector_type(4)));
typedef short v8s __attribute__((ext_vector_type(8)));

__device__ __forceinline__ unsigned short f2bf(float f) {
    __hip_bfloat16 h = __float2bfloat16(f);
    return *reinterpret_cast<unsigned short*>(&h);
}

__device__ __forceinline__ void async_ld16(const void* g, void* l) {
    __builtin_amdgcn_global_load_lds(
        (__attribute__((address_space(1))) void*)(void*)g,
        (__attribute__((address_space(3))) void*)l,
        16, 0, 0);
}

// ------- fused converters: blocks [0,4096) = W->bf16; [4096,8192) = x->xT -------
__global__ void conv_all(const float* __restrict__ W, unsigned short* __restrict__ Wb,
                         const float* __restrict__ x, unsigned short* __restrict__ xT) {
    if (blockIdx.x < 4096) {
        int i = (blockIdx.x * 256 + threadIdx.x) * 4;
        float4 v = *(const float4*)(W + i);
        ushort4 o;
        o.x = f2bf(v.x); o.y = f2bf(v.y); o.z = f2bf(v.z); o.w = f2bf(v.w);
        *(ushort4*)(Wb + i) = o;
        return;
    }
    const int t = blockIdx.x - 4096;
    const int k0 = (t & 31) * 64, d0 = ((t >> 5) & 15) * 64, bb = t >> 9;
    __shared__ unsigned short tile[64][68];   // pad 68 to break bank alignment
    const int tid = threadIdx.x;
    const int tx = tid & 15, ty = tid >> 4;
    const float* xp = x + (size_t)bb * K_ * D_;
#pragma unroll
    for (int r = 0; r < 4; r++) {
        int row = ty + r * 16;
        float4 v = *(const float4*)(xp + (size_t)(k0 + row) * D_ + d0 + tx * 4);
        tile[row][tx * 4 + 0] = f2bf(v.x);
        tile[row][tx * 4 + 1] = f2bf(v.y);
        tile[row][tx * 4 + 2] = f2bf(v.z);
        tile[row][tx * 4 + 3] = f2bf(v.w);
    }
    __syncthreads();
    unsigned short* op = xT + (size_t)bb * D_ * K_;
#pragma unroll
    for (int r = 0; r < 4; r++) {
        int dcol = ty + r * 16;
        ushort4 u;
        u.x = tile[tx * 4 + 0][dcol];
        u.y = tile[tx * 4 + 1][dcol];
        u.z = tile[tx * 4 + 2][dcol];
        u.w = tile[tx * 4 + 3][dcol];
        *(ushort4*)(op + (size_t)(d0 + dcol) * K_ + k0 + tx * 4) = u;
    }
}

// ---------------- GEMM + bias + sigmoid (+ fused chunk-scan pass1) ----------------
// R8 RESTRUCTURE for 2 WGs/CU (the un-tried lever: independent-WG overlap, m97
// mechanism — 1-WG/CU barriers serialized reads vs MFMA at 33% MfmaUtil across
// all R5-R7 schedule variants):
//   tile 128(M=t) x 256(N=d), grid 512 = 2 WGs/CU (one batch per XCD, bijective),
//   8 waves (2M x 4N), wave tile 64x64 (acc 4x4 = 64 VGPR, was 128), BK=32
//   double-buffered: LDS ring 48 KiB, static 64 KiB (union w/ epilogue scratch)
//   -> 2 WGs/CU at <=128 VGPR (launch_bounds 512,4).
// Schedule: ONE barrier per half: {8 frag ds_reads | 3 stage gloads -> lgkmcnt(0)
// -> 16 MFMA -> vmcnt(0) -> barrier}. Blocking waits are covered by the other WG.
// WAR: stage targets buf nxt; next half's stage into buf cur is issued only
// after the barrier (all waves' reads of cur done).
// Epilogue: per wave = exactly chunk c = tM*2+wm x 64 d-cols; two 32-col passes,
// 8 KiB wave-private XOR'd scratch; scan split t in 2 halves across lane pairs
// (lane&32) + __shfl_xor(32) affine combine.
__launch_bounds__(512, 4)
__global__ void gemm_sig(const unsigned short* __restrict__ Wb,
                         const unsigned short* __restrict__ xT,
                         const float* __restrict__ bias,
                         const float* __restrict__ xf,
                         float* __restrict__ lam,
                         float* __restrict__ Ac,
                         float* __restrict__ Uc,
                         int fuse) {
    __shared__ __align__(16) unsigned char lds_raw[65536];
    unsigned short* As = (unsigned short*)lds_raw;             // [2][128*32] hw = 16 KiB
    unsigned short* Bs = (unsigned short*)(lds_raw + 16384);   // [2][256*32] hw = 32 KiB

    // XCD-chunked bijective swizzle (nwg=512): one batch b per XCD.
    const int bid = blockIdx.x;
    const int lid = (bid & 7) * 64 + (bid >> 3);
    const int bb = lid >> 6;            // batch
    const int rr = lid & 63;
    const int tM = rr >> 2;             // 16 M-tiles (128 rows of t)
    const int tN = rr & 3;              // 4 N-tiles (256 cols of d)

    const int tid = threadIdx.x;
    const int w = tid >> 6;             // wave 0..7
    const int lane = tid & 63;
    const int wm = w >> 2;              // 0..1  (M, 64 rows each)
    const int wn = w & 3;               // 0..3  (N, 64 cols each)
    const int quad = lane >> 4;
    const int l16 = lane & 15;

    const unsigned short* Ag = Wb + (size_t)(tM * 128) * K_;
    const unsigned short* Bg = xT + (size_t)bb * D_ * K_ + (size_t)(tN * 256) * K_;

    // staging lane constants (1 KiB block = 16 rows x 4 16B granules; source XOR
    // matches the ds_read-side XOR — rule #21, measured 0 conflicts since R1)
    const int srow = lane >> 2;
    const int sgk8 = ((lane & 3) ^ ((lane >> 3) & 3)) * 8;

    const int frg = (quad ^ ((l16 >> 1) & 3)) * 8;
    const int a_hw = (wm * 64 + l16) * 32 + frg;   // + i*512
    const int b_hw = (wn * 64 + l16) * 32 + frg;   // + j*512

    v4f acc[4][4];
#pragma unroll
    for (int i = 0; i < 4; i++)
#pragma unroll
        for (int j = 0; j < 4; j++) acc[i][j] = (v4f)0.f;

    // stage half hh (BK=32) into buffer bufi: A 128x32 (1 load/thr), B 256x32 (2)
#define STAGE_(bufi, hh)                                                                    \
    do {                                                                                    \
        const int ko_ = (hh) * 32;                                                          \
        async_ld16(Ag + (size_t)(w * 16 + srow) * K_ + ko_ + sgk8,                          \
                   As + (bufi) * 4096 + w * 512);                                           \
        async_ld16(Bg + (size_t)(w * 16 + srow) * K_ + ko_ + sgk8,                          \
                   Bs + (bufi) * 8192 + w * 512);                                           \
        async_ld16(Bg + (size_t)((8 + w) * 16 + srow) * K_ + ko_ + sgk8,                    \
                   Bs + (bufi) * 8192 + (8 + w) * 512);                                     \
    } while (0)

    STAGE_(0, 0);
    asm volatile("s_waitcnt vmcnt(0)");
    asm volatile("s_barrier" ::: "memory");

    v8s af[4], bf[4];
    const int H = K_ / 32;              // 64 halves
    for (int h = 0; h < H - 1; ++h) {
        const int cur = h & 1, nxt = cur ^ 1;
        const unsigned short* Ac_ = As + cur * 4096;
        const unsigned short* Bc_ = Bs + cur * 8192;
#pragma unroll
        for (int i = 0; i < 4; i++) af[i] = *(const v8s*)(&Ac_[a_hw + i * 512]);
#pragma unroll
        for (int j = 0; j < 4; j++) bf[j] = *(const v8s*)(&Bc_[b_hw + j * 512]);
        STAGE_(nxt, h + 1);
        asm volatile("s_waitcnt lgkmcnt(0)");
        __builtin_amdgcn_sched_barrier(0);
        __builtin_amdgcn_s_setprio(1);
#pragma unroll
        for (int i = 0; i < 4; i++)
#pragma unroll
            for (int j = 0; j < 4; j++)
                acc[i][j] = __builtin_amdgcn_mfma_f32_16x16x32_bf16(af[i], bf[j], acc[i][j], 0, 0, 0);
        __builtin_amdgcn_s_setprio(0);
        asm volatile("s_waitcnt vmcnt(0)");   // next buffer staged
        asm volatile("s_barrier" ::: "memory");
    }
    {   // peeled last half (no staging)
        const int cur = (H - 1) & 1;
        const unsigned short* Ac_ = As + cur * 4096;
        const unsigned short* Bc_ = Bs + cur * 8192;
#pragma unroll
        for (int i = 0; i < 4; i++) af[i] = *(const v8s*)(&Ac_[a_hw + i * 512]);
#pragma unroll
        for (int j = 0; j < 4; j++) bf[j] = *(const v8s*)(&Bc_[b_hw + j * 512]);
        asm volatile("s_waitcnt lgkmcnt(0)");
        __builtin_amdgcn_sched_barrier(0);
        __builtin_amdgcn_s_setprio(1);
#pragma unroll
        for (int i = 0; i < 4; i++)
#pragma unroll
            for (int j = 0; j < 4; j++)
                acc[i][j] = __builtin_amdgcn_mfma_f32_16x16x32_bf16(af[i], bf[j], acc[i][j], 0, 0, 0);
        __builtin_amdgcn_s_setprio(0);
        asm volatile("s_barrier" ::: "memory");   // all waves done with ring -> scratch safe
    }
#undef STAGE_

    float* out = lam + (size_t)bb * K_ * D_;
    const int c = tM * 2 + wm;          // this wave's (only) chunk
    const int t0 = c * 64;

    if (fuse) {
        float* Swp = (float*)lds_raw + w * 2048;   // 8 KiB wave-private scratch
#pragma unroll
        for (int p = 0; p < 2; ++p) {   // two 32-col passes (j = 2p, 2p+1)
#pragma unroll
            for (int jj = 0; jj < 2; ++jj) {
                const int j = p * 2 + jj;
#pragma unroll
                for (int i = 0; i < 4; i++) {
                    const int rowb = t0 + i * 16 + quad * 4;
#pragma unroll
                    for (int r = 0; r < 4; r++) {
                        float bt = bias[rowb + r];
                        const int colg = tN * 256 + wn * 64 + j * 16 + l16;
                        float v = acc[i][j][r] + bt;
                        float sg = 1.f / (1.f + __expf(-v));
                        out[(size_t)(rowb + r) * D_ + colg] = sg;
                        Swp[(i * 16 + quad * 4 + r) * 32 + ((jj * 16 + l16) ^ (quad * 8))] = sg;
                    }
                }
            }
            asm volatile("s_waitcnt lgkmcnt(0)");
            __builtin_amdgcn_sched_barrier(0);
            // scan: 64 lanes, 32 cols, t split in 2 halves across lane&32
            const int col32 = lane & 31;
            const int h2 = lane >> 5;
            const int dcol = tN * 256 + wn * 64 + p * 32 + col32;
            const float* xg = xf + ((size_t)bb * K_ + t0 + h2 * 32) * D_ + dcol;
            float A = 1.f, U = 0.f;
#pragma unroll 8
            for (int tt = 0; tt < 32; tt++) {
                const int trow = h2 * 32 + tt;
                float l = Swp[trow * 32 + (col32 ^ (((trow >> 2) & 3) * 8))];
                float xv = xg[(size_t)tt * D_];
                A *= l;
                U = l * U + (1.f - l) * xv;
            }
            // affine combine: (A1,U1) after (A0,U0): Af = A1*A0, Uf = A1*U0 + U1
            float Apr = __shfl_xor(A, 32);
            float Upr = __shfl_xor(U, 32);
            if (h2 == 0) {
                float Af = Apr * A;
                float Uf = Apr * U + Upr;
                size_t oi = ((size_t)bb * NC + c) * D_ + dcol;
                Ac[oi] = Af;
                Uc[oi] = Uf;
            }
            asm volatile("s_waitcnt lgkmcnt(0)");   // pass p reads done before p+1 writes
            __builtin_amdgcn_sched_barrier(0);
        }
    } else {
        // plain epilogue (fallback when ws too small for fused Ac/Uc placement)
#pragma unroll
        for (int i = 0; i < 4; i++) {
            int rowb = t0 + i * 16 + quad * 4;
#pragma unroll
            for (int r = 0; r < 4; r++) {
                float bt = bias[rowb + r];
#pragma unroll
                for (int j = 0; j < 4; j++) {
                    int col = tN * 256 + wn * 64 + j * 16 + l16;
                    float v = acc[i][j][r] + bt;
                    out[(size_t)(rowb + r) * D_ + col] = 1.f / (1.f + __expf(-v));
                }
            }
        }
    }
}

// -------- scan pass 1 (FALLBACK ONLY): per-(b,chunk,d2) affine composition --------
__global__ void scan_pass1(const float* __restrict__ lam, const float* __restrict__ x,
                           float* __restrict__ Ac, float* __restrict__ Uc) {
    int id = blockIdx.x * 256 + threadIdx.x;   // B*NC*D/2 = 131072
    int d2 = (id & 511) * 2;
    int c = (id >> 9) & (NC - 1);
    int bb = id >> 14;
    const float* lp = lam + ((size_t)bb * K_ + (size_t)c * TC) * D_ + d2;
    const float* xp = x   + ((size_t)bb * K_ + (size_t)c * TC) * D_ + d2;
    float2 A = make_float2(1.f, 1.f), U = make_float2(0.f, 0.f);
#pragma unroll 8
    for (int t = 0; t < TC; t++) {
        float2 l  = *(const float2*)(lp + (size_t)t * D_);
        float2 xv = *(const float2*)(xp + (size_t)t * D_);
        A.x *= l.x; A.y *= l.y;
        U.x = l.x * U.x + (1.f - l.x) * xv.x;
        U.y = l.y * U.y + (1.f - l.y) * xv.y;
    }
    size_t oi = ((size_t)bb * NC + c) * D_ + d2;
    *(float2*)(Ac + oi) = A;
    *(float2*)(Uc + oi) = U;
}

// -------- scan pass 3 (absorbs pass 2): prefix over chunks + replay --------
__launch_bounds__(256)
__global__ void scan_pass3(const float* __restrict__ x,
                           const float* __restrict__ Ac, const float* __restrict__ Uc,
                           float* __restrict__ lamout) {
    int id = blockIdx.x * 256 + threadIdx.x;   // B*NC*D/2 = 131072
    int d = (id & 511) * 2;
    int c = (id >> 9) & (NC - 1);
    int bb = id >> 14;
    float2 s = make_float2(0.f, 0.f);
    for (int j = 0; j < c; j++) {
        size_t ji = ((size_t)bb * NC + j) * D_ + d;
        float2 A = *(const float2*)(Ac + ji);
        float2 U = *(const float2*)(Uc + ji);
        s.x = A.x * s.x + U.x;
        s.y = A.y * s.y + U.y;
    }
    float* lp = lamout + ((size_t)bb * K_ + (size_t)c * TC) * D_ + d;
    const float* xp = x + ((size_t)bb * K_ + (size_t)c * TC) * D_ + d;
#pragma unroll 8
    for (int t = 0; t < TC; t++) {
        float2 l  = *(const float2*)(lp + (size_t)t * D_);
        float2 xv = *(const float2*)(xp + (size_t)t * D_);
        s.x = l.x * s.x + (1.f - l.x) * xv.x;
        s.y = l.y * s.y + (1.f - l.y) * xv.y;
        __builtin_nontemporal_store(s.x, lp + (size_t)t * D_);
        __builtin_nontemporal_store(s.y, lp + (size_t)t * D_ + 1);
    }
}

extern "C" void kernel_launch(void* const* d_in, const int* in_sizes, int n_in,
                              void* d_out, int out_size, void* d_ws, size_t ws_size,
                              hipStream_t stream) {
    const float* x    = (const float*)d_in[0];
    const float* W    = (const float*)d_in[1];
    const float* bias = (const float*)d_in[2];
    float* out = (float*)d_out;
    char* ws = (char*)d_ws;

    unsigned short* xT = (unsigned short*)ws;                       // 32 MiB  [B][D][K] bf16
    unsigned short* Wb = (unsigned short*)(ws + 33554432);          // 8 MiB   [K][K] bf16

    // Fused path needs Ac/Uc live DURING gemm (other WGs still read Wb/xT), so
    // they must sit in fresh ws after Wb: needs 40 MiB + 2 MiB = 44040192 B.
    const int fuse = (ws_size >= 44040192u) ? 1 : 0;
    float* Ac, * Uc;
    if (fuse) {
        Ac = (float*)(ws + 41943040);
        Uc = (float*)(ws + 41943040 + 1048576);
    } else {
        Ac = (float*)(ws + 33554432);                // overlay Wb (dead post-gemm)
        Uc = (float*)(ws + 33554432 + 1048576);
    }

    conv_all<<<dim3(8192), 256, 0, stream>>>(W, Wb, x, xT);
    // lam goes into d_out; pass3 overwrites it in place with the final scan output
    gemm_sig<<<dim3(512), dim3(512), 0, stream>>>(Wb, xT, bias, x, out, Ac, Uc, fuse);
    if (!fuse)
        scan_pass1<<<dim3(B_ * NC * D_ / 2 / 256), 256, 0, stream>>>(out, x, Ac, Uc);
    scan_pass3<<<dim3(B_ * NC * D_ / 2 / 256), 256, 0, stream>>>(x, Ac, Uc, out);
}